// Round 4
// baseline (761.363 us; speedup 1.0000x reference)
//
#include <hip/hip_runtime.h>

#define C_IN 10
#define C_OUT 64
#define BN_EPS 1e-3f

// ======================= shared small kernels ==============================

__global__ __launch_bounds__(256) void zero_u32_kernel(unsigned* __restrict__ p, int n) {
    int i = blockIdx.x * 256 + threadIdx.x;
    int s = gridDim.x * 256;
    for (; i < n; i += s) p[i] = 0u;
}

// ===========================================================================
// FULL-SORT PATH: counting-sort points by pillar id, then one wave per pillar
// with register max. No LDS in the pool, no atomics in the pool.
// ws layout (u32): cur[M] | bsum[nbB] | pad | rec[n]
// ===========================================================================

// 600K-counter histogram (global atomics, low contention: ~5 per counter)
__global__ __launch_bounds__(256) void hist_full_kernel(const int* __restrict__ idx, int n,
                                                        unsigned* __restrict__ cur) {
    int stride = gridDim.x * 256;
    for (int i = blockIdx.x * 256 + threadIdx.x; i < n; i += stride)
        atomicAdd(&cur[(unsigned)idx[i]], 1u);
}

// scan stage 1: per-256-block sums
__global__ __launch_bounds__(256) void reduce_block_kernel(const unsigned* __restrict__ cur,
                                                           unsigned* __restrict__ bsum, int M) {
    __shared__ unsigned s[256];
    int t = threadIdx.x;
    int g = blockIdx.x * 256 + t;
    s[t] = (g < M) ? cur[g] : 0u;
    __syncthreads();
    for (int off = 128; off > 0; off >>= 1) {
        if (t < off) s[t] += s[t + off];
        __syncthreads();
    }
    if (t == 0) bsum[blockIdx.x] = s[0];
}

// scan stage 2: single-block in-place exclusive scan of bsum[nbB]
__global__ __launch_bounds__(256) void scan_small_kernel(unsigned* __restrict__ bsum, int nbB) {
    __shared__ unsigned partial[256];
    __shared__ unsigned base[256];
    int t = threadIdx.x;
    int per = (nbB + 255) / 256;
    int lo = t * per, hi = lo + per; if (hi > nbB) hi = nbB;
    unsigned s = 0;
    for (int i = lo; i < hi; ++i) s += bsum[i];
    partial[t] = s;
    __syncthreads();
    if (t == 0) {
        unsigned acc = 0;
        for (int k = 0; k < 256; ++k) { base[k] = acc; acc += partial[k]; }
    }
    __syncthreads();
    unsigned acc = base[t];
    for (int i = lo; i < hi; ++i) { unsigned v = bsum[i]; bsum[i] = acc; acc += v; }
}

// scan stage 3: per-block exclusive scan (in place) + block base
__global__ __launch_bounds__(256) void scan_block_kernel(unsigned* __restrict__ cur,
                                                         const unsigned* __restrict__ bsum, int M) {
    __shared__ unsigned s[256];
    int t = threadIdx.x;
    int g = blockIdx.x * 256 + t;
    unsigned v = (g < M) ? cur[g] : 0u;
    s[t] = v;
    __syncthreads();
    for (int off = 1; off < 256; off <<= 1) {
        unsigned x = (t >= off) ? s[t - off] : 0u;
        __syncthreads();
        s[t] += x;
        __syncthreads();
    }
    if (g < M) cur[g] = s[t] - v + bsum[blockIdx.x];   // exclusive + base
}

// scatter point ids into pillar-sorted order; afterwards cur[pid] = segment END
__global__ __launch_bounds__(256) void scatter_full_kernel(const int* __restrict__ idx, int n,
                                                           unsigned* __restrict__ cur,
                                                           unsigned* __restrict__ rec) {
    int stride = gridDim.x * 256;
    for (int i = blockIdx.x * 256 + threadIdx.x; i < n; i += stride) {
        unsigned pos = atomicAdd(&cur[(unsigned)idx[i]], 1u);
        rec[pos] = (unsigned)i;
    }
}

// pool: one wave per pillar, lane = channel, register running max.
__global__ __launch_bounds__(256) void pool_full_kernel(
    const float* __restrict__ pts,
    const unsigned* __restrict__ rec,
    const unsigned* __restrict__ cur,     // ends; start = cur[pid-1]
    const float* __restrict__ W,
    const float* __restrict__ gamma,
    const float* __restrict__ beta,
    const float* __restrict__ mean,
    const float* __restrict__ var,
    float* __restrict__ out, int M)
{
    const int lane = threadIdx.x & 63;
    const int pid  = (blockIdx.x * 256 + threadIdx.x) >> 6;
    if (pid >= M) return;

    float w[C_IN];
#pragma unroll
    for (int j = 0; j < C_IN; ++j) w[j] = W[j * C_OUT + lane];
    const float scale = gamma[lane] * rsqrtf(var[lane] + BN_EPS);
    const float shift = fmaf(-mean[lane], scale, beta[lane]);

    const unsigned end   = cur[pid];
    const unsigned start = (pid == 0) ? 0u : cur[pid - 1];

    float m = 0.f;
    for (unsigned base = start; base < end; base += 64) {
        const int nn = (int)min(64u, end - base);
        const unsigned rcv = (base + (unsigned)lane < end) ? rec[base + lane] : 0u;

        int i = 0;
        for (; i + 1 < nn; i += 2) {          // 2-way unroll: both rows' loads in flight
            const unsigned p0 = (unsigned)__shfl((int)rcv, i);
            const unsigned p1 = (unsigned)__shfl((int)rcv, i + 1);
            const float2* f0 = (const float2*)(pts + (size_t)p0 * C_IN);
            const float2* f1 = (const float2*)(pts + (size_t)p1 * C_IN);
            float2 a0 = f0[0], a1 = f0[1], a2 = f0[2], a3 = f0[3], a4 = f0[4];
            float2 b0 = f1[0], b1 = f1[1], b2 = f1[2], b3 = f1[3], b4 = f1[4];
            float h0 = 0.f, h1 = 0.f;
            h0 = fmaf(a0.x, w[0], h0); h0 = fmaf(a0.y, w[1], h0);
            h0 = fmaf(a1.x, w[2], h0); h0 = fmaf(a1.y, w[3], h0);
            h0 = fmaf(a2.x, w[4], h0); h0 = fmaf(a2.y, w[5], h0);
            h0 = fmaf(a3.x, w[6], h0); h0 = fmaf(a3.y, w[7], h0);
            h0 = fmaf(a4.x, w[8], h0); h0 = fmaf(a4.y, w[9], h0);
            h1 = fmaf(b0.x, w[0], h1); h1 = fmaf(b0.y, w[1], h1);
            h1 = fmaf(b1.x, w[2], h1); h1 = fmaf(b1.y, w[3], h1);
            h1 = fmaf(b2.x, w[4], h1); h1 = fmaf(b2.y, w[5], h1);
            h1 = fmaf(b3.x, w[6], h1); h1 = fmaf(b3.y, w[7], h1);
            h1 = fmaf(b4.x, w[8], h1); h1 = fmaf(b4.y, w[9], h1);
            h0 = fmaxf(fmaf(h0, scale, shift), 0.f);
            h1 = fmaxf(fmaf(h1, scale, shift), 0.f);
            m = fmaxf(m, fmaxf(h0, h1));
        }
        if (i < nn) {                          // tail
            const unsigned p0 = (unsigned)__shfl((int)rcv, i);
            const float2* f0 = (const float2*)(pts + (size_t)p0 * C_IN);
            float2 a0 = f0[0], a1 = f0[1], a2 = f0[2], a3 = f0[3], a4 = f0[4];
            float h0 = 0.f;
            h0 = fmaf(a0.x, w[0], h0); h0 = fmaf(a0.y, w[1], h0);
            h0 = fmaf(a1.x, w[2], h0); h0 = fmaf(a1.y, w[3], h0);
            h0 = fmaf(a2.x, w[4], h0); h0 = fmaf(a2.y, w[5], h0);
            h0 = fmaf(a3.x, w[6], h0); h0 = fmaf(a3.y, w[7], h0);
            h0 = fmaf(a4.x, w[8], h0); h0 = fmaf(a4.y, w[9], h0);
            m = fmaxf(m, fmaxf(fmaf(h0, scale, shift), 0.f));
        }
    }
    out[(size_t)pid * C_OUT + lane] = m;
}

// ===========================================================================
// FALLBACK 1: bucket path (round-3 kernel set)
// ===========================================================================
#define BP 128
#define MAX_NB 4704
#define CHUNK 256
#define FSTRIDE 11

__global__ __launch_bounds__(256) void hist_kernel(const int* __restrict__ idx, int n,
                                                   unsigned* __restrict__ hist, int nb) {
    __shared__ unsigned h[MAX_NB];
    for (int i = threadIdx.x; i < nb; i += 256) h[i] = 0u;
    __syncthreads();
    int stride = gridDim.x * 256;
    for (int i = blockIdx.x * 256 + threadIdx.x; i < n; i += stride)
        atomicAdd(&h[((unsigned)idx[i]) >> 7], 1u);
    __syncthreads();
    for (int i = threadIdx.x; i < nb; i += 256) {
        unsigned v = h[i];
        if (v) atomicAdd(&hist[i], v);
    }
}

__global__ __launch_bounds__(256) void scan_kernel(const unsigned* __restrict__ hist,
                                                   unsigned* __restrict__ cursor, int nb) {
    __shared__ unsigned partial[256];
    __shared__ unsigned base[256];
    int per = (nb + 255) / 256;
    int lo = threadIdx.x * per;
    int hi = lo + per; if (hi > nb) hi = nb;
    unsigned s = 0;
    for (int i = lo; i < hi; ++i) s += hist[i];
    partial[threadIdx.x] = s;
    __syncthreads();
    if (threadIdx.x == 0) {
        unsigned acc = 0;
        for (int t = 0; t < 256; ++t) { base[t] = acc; acc += partial[t]; }
    }
    __syncthreads();
    unsigned acc = base[threadIdx.x];
    for (int i = lo; i < hi; ++i) { cursor[i] = acc; acc += hist[i]; }
}

__global__ __launch_bounds__(256) void scatter_ids_kernel(const int* __restrict__ idx, int n,
                                                          unsigned* __restrict__ cursor,
                                                          unsigned* __restrict__ rec) {
    int stride = gridDim.x * 256;
    for (int i = blockIdx.x * 256 + threadIdx.x; i < n; i += stride) {
        unsigned pid = (unsigned)idx[i];
        unsigned pos = atomicAdd(&cursor[pid >> 7], 1u);
        rec[pos] = ((pid & (BP - 1)) << 22) | (unsigned)i;
    }
}

__global__ __launch_bounds__(256) void pool_kernel(
    const float* __restrict__ pts, const unsigned* __restrict__ rec,
    const unsigned* __restrict__ cursor, const float* __restrict__ W,
    const float* __restrict__ gamma, const float* __restrict__ beta,
    const float* __restrict__ mean, const float* __restrict__ var,
    float* __restrict__ out, int M)
{
    __shared__ unsigned smax[BP * C_OUT];
    __shared__ float    feat[CHUNK * FSTRIDE];
    __shared__ unsigned slp[CHUNK];
    const int b = blockIdx.x, t = threadIdx.x;
    const int lane = t & 63, wid = t >> 6;
    for (int i = t; i < BP * C_OUT; i += 256) smax[i] = 0u;
    float w[C_IN];
#pragma unroll
    for (int j = 0; j < C_IN; ++j) w[j] = W[j * C_OUT + lane];
    const float scale = gamma[lane] * rsqrtf(var[lane] + BN_EPS);
    const float shift = fmaf(-mean[lane], scale, beta[lane]);
    const unsigned start = (b == 0) ? 0u : cursor[b - 1];
    const int total = (int)(cursor[b] - start);
    float fr[C_IN]; unsigned rcr = 0; bool hav = false;
    if (t < total) {
        rcr = rec[start + t];
        const float2* f2 = (const float2*)(pts + (size_t)(rcr & 0x3FFFFFu) * C_IN);
#pragma unroll
        for (int j = 0; j < 5; ++j) { float2 v = f2[j]; fr[2*j] = v.x; fr[2*j+1] = v.y; }
        hav = true;
    }
    for (int chunk = 0; chunk < total; chunk += CHUNK) {
        const int nrec = min(CHUNK, total - chunk);
        __syncthreads();
        if (hav) {
            slp[t] = rcr >> 22;
#pragma unroll
            for (int j = 0; j < C_IN; ++j) feat[t * FSTRIDE + j] = fr[j];
        }
        __syncthreads();
        const int nr = chunk + CHUNK + t;
        hav = false;
        if (nr < total) {
            rcr = rec[start + nr];
            const float2* f2 = (const float2*)(pts + (size_t)(rcr & 0x3FFFFFu) * C_IN);
#pragma unroll
            for (int j = 0; j < 5; ++j) { float2 v = f2[j]; fr[2*j] = v.x; fr[2*j+1] = v.y; }
            hav = true;
        }
        for (int i = wid; i < nrec; i += 4) {
            const unsigned lp = slp[i];
            const float* f = &feat[i * FSTRIDE];
            float h = 0.f;
#pragma unroll
            for (int j = 0; j < C_IN; ++j) h = fmaf(f[j], w[j], h);
            h = fmaxf(fmaf(h, scale, shift), 0.f);
            atomicMax(&smax[(lp << 6) + lane], __float_as_uint(h));
        }
    }
    __syncthreads();
    const float4* s4 = (const float4*)smax;
    float4* o4 = (float4*)out;
    const size_t base4 = (size_t)b * (BP * C_OUT / 4);
    const size_t tot4  = (size_t)M * (C_OUT / 4);
    for (int i = t; i < BP * C_OUT / 4; i += 256) {
        size_t g = base4 + (size_t)i;
        if (g < tot4) o4[g] = s4[i];
    }
}

// ===========================================================================
// FALLBACK 2: global atomic scatter (round-0)
// ===========================================================================
__global__ __launch_bounds__(256) void zero_out_kernel(float4* __restrict__ out4, int n4) {
    int i = blockIdx.x * blockDim.x + threadIdx.x;
    int stride = gridDim.x * blockDim.x;
    float4 z = make_float4(0.f, 0.f, 0.f, 0.f);
    for (int j = i; j < n4; j += stride) out4[j] = z;
}

__global__ __launch_bounds__(256) void pillar_scatter_kernel(
    const float* __restrict__ pts, const int* __restrict__ idx,
    const float* __restrict__ W, const float* __restrict__ gamma,
    const float* __restrict__ beta, const float* __restrict__ mean,
    const float* __restrict__ var, unsigned int* __restrict__ out, int npoints)
{
    const int lane = threadIdx.x & 63;
    float w[C_IN];
#pragma unroll
    for (int j = 0; j < C_IN; ++j) w[j] = W[j * C_OUT + lane];
    const float scale = gamma[lane] * rsqrtf(var[lane] + BN_EPS);
    const float shift = fmaf(-mean[lane], scale, beta[lane]);
    const int wave_id = (blockIdx.x * blockDim.x + threadIdx.x) >> 6;
    const int nwaves  = (gridDim.x * blockDim.x) >> 6;
    for (int p = wave_id; p < npoints; p += nwaves) {
        const float* f = pts + (size_t)p * C_IN;
        float h = 0.f;
#pragma unroll
        for (int j = 0; j < C_IN; ++j) h = fmaf(f[j], w[j], h);
        h = fmaxf(fmaf(h, scale, shift), 0.f);
        atomicMax(&out[(size_t)idx[p] * C_OUT + lane], __float_as_uint(h));
    }
}

// ===========================================================================

extern "C" void kernel_launch(void* const* d_in, const int* in_sizes, int n_in,
                              void* d_out, int out_size, void* d_ws, size_t ws_size,
                              hipStream_t stream) {
    const float* pts   = (const float*)d_in[0];
    const int*   idx   = (const int*)  d_in[1];
    const float* W     = (const float*)d_in[2];
    const float* gamma = (const float*)d_in[3];
    const float* beta  = (const float*)d_in[4];
    const float* mean  = (const float*)d_in[5];
    const float* var   = (const float*)d_in[6];

    const int npoints = in_sizes[0] / C_IN;     // 3,000,000
    const int M       = out_size / C_OUT;       // 600,000 pillars
    const int nbB     = (M + 255) / 256;        // scan blocks (2344)

    // full-sort ws layout (u32): cur[M] | bsum[nbB] | pad | rec[npoints]
    const size_t rec_off_full = (((size_t)M + (size_t)nbB) + 63) & ~(size_t)63;
    const size_t need_full    = (rec_off_full + (size_t)npoints) * sizeof(unsigned);

    if (ws_size >= need_full) {
        unsigned* cur  = (unsigned*)d_ws;
        unsigned* bsum = cur + M;
        unsigned* rec  = (unsigned*)d_ws + rec_off_full;

        zero_u32_kernel   <<<(M + 255) / 256 < 2048 ? (M + 255) / 256 : 2048, 256, 0, stream>>>(cur, M);
        hist_full_kernel  <<<2048, 256, 0, stream>>>(idx, npoints, cur);
        reduce_block_kernel<<<nbB, 256, 0, stream>>>(cur, bsum, M);
        scan_small_kernel <<<1, 256, 0, stream>>>(bsum, nbB);
        scan_block_kernel <<<nbB, 256, 0, stream>>>(cur, bsum, M);
        scatter_full_kernel<<<2048, 256, 0, stream>>>(idx, npoints, cur, rec);
        pool_full_kernel  <<<(M + 3) / 4, 256, 0, stream>>>(pts, rec, cur, W, gamma, beta,
                                                            mean, var, (float*)d_out, M);
        return;
    }

    // fallback 1: bucket path
    const int nb = (M + BP - 1) / BP;
    const size_t rec_off    = ((size_t)(2 * nb) + 63) & ~(size_t)63;
    const size_t need_bytes = (rec_off + (size_t)npoints) * sizeof(unsigned);
    if ((nb <= MAX_NB) && (npoints < (1 << 22)) && (ws_size >= need_bytes)) {
        unsigned* cursor = (unsigned*)d_ws;
        unsigned* hist   = cursor + nb;
        unsigned* rec    = (unsigned*)d_ws + rec_off;
        zero_u32_kernel<<<(2 * nb + 255) / 256, 256, 0, stream>>>(cursor, 2 * nb);
        hist_kernel<<<256, 256, 0, stream>>>(idx, npoints, hist, nb);
        scan_kernel<<<1, 256, 0, stream>>>(hist, cursor, nb);
        scatter_ids_kernel<<<2048, 256, 0, stream>>>(idx, npoints, cursor, rec);
        pool_kernel<<<nb, 256, 0, stream>>>(pts, rec, cursor, W, gamma, beta, mean, var,
                                            (float*)d_out, M);
        return;
    }

    // fallback 2: global atomics
    zero_out_kernel<<<2048, 256, 0, stream>>>((float4*)d_out, out_size / 4);
    pillar_scatter_kernel<<<2048, 256, 0, stream>>>(
        pts, idx, W, gamma, beta, mean, var, (unsigned int*)d_out, npoints);
}

// Round 5
// 243.928 us; speedup vs baseline: 3.1213x; 3.1213x over previous
//
#include <hip/hip_runtime.h>

#define C_IN 10
#define C_OUT 64
#define BN_EPS 1e-3f

#define BP    128         // pillars per bucket (idx>>7)
#define CB    256         // chunk blocks for hist/scatter
#define NBMAX 4704        // max buckets supported by fast path
#define WIN   256         // points staged per window
#define FSTR  12          // feat row stride in floats (48 B, b128-aligned)
#define MAXB  1536        // fine-sort capacity per bucket (lambda=640, +35 sigma)
#define TS    2048        // scan tile size

// ===========================================================================
// ATOMIC-FREE SORT PROLOGUE
// ws (u32): ghist[NB*CB] (scanned in place) | tsum[nt] | bstart[NB+1] | rec[n]
// ===========================================================================

// K1: per-chunk LDS histogram -> ghist[k*CB + b]
__global__ __launch_bounds__(256) void k1_hist(const int* __restrict__ idx, int n, int chunk,
                                               unsigned* __restrict__ ghist, int NB) {
    __shared__ unsigned h[NBMAX];
    const int b = blockIdx.x, t = threadIdx.x;
    for (int i = t; i < NB; i += 256) h[i] = 0u;
    __syncthreads();
    const int lo = b * chunk;
    const int hi = min(n, lo + chunk);
    for (int i = lo + t; i < hi; i += 256)
        atomicAdd(&h[((unsigned)idx[i]) >> 7], 1u);
    __syncthreads();
    for (int k = t; k < NB; k += 256) ghist[(size_t)k * CB + b] = h[k];
}

// K2a: per-tile sums
__global__ __launch_bounds__(256) void k2a_reduce(const unsigned* __restrict__ g, int G,
                                                  unsigned* __restrict__ tsum) {
    __shared__ unsigned s[256];
    const int t = threadIdx.x;
    const int base = blockIdx.x * TS + t * 8;
    unsigned acc = 0;
#pragma unroll
    for (int j = 0; j < 8; ++j) { int gi = base + j; if (gi < G) acc += g[gi]; }
    s[t] = acc; __syncthreads();
    for (int off = 128; off > 0; off >>= 1) { if (t < off) s[t] += s[t + off]; __syncthreads(); }
    if (t == 0) tsum[blockIdx.x] = s[0];
}

// K2b: exclusive scan of tsum in place (single block)
__global__ __launch_bounds__(256) void k2b_scan(unsigned* __restrict__ tsum, int nt) {
    __shared__ unsigned partial[256], basev[256];
    const int t = threadIdx.x;
    const int per = (nt + 255) / 256;
    const int lo = t * per, hi = min(nt, lo + per);
    unsigned s = 0;
    for (int i = lo; i < hi; ++i) s += tsum[i];
    partial[t] = s; __syncthreads();
    if (t == 0) { unsigned a = 0; for (int k = 0; k < 256; ++k) { basev[k] = a; a += partial[k]; } }
    __syncthreads();
    unsigned a = basev[t];
    for (int i = lo; i < hi; ++i) { unsigned v = tsum[i]; tsum[i] = a; a += v; }
}

// K2c: apply per-tile exclusive scan in place; emit bucket starts
__global__ __launch_bounds__(256) void k2c_apply(unsigned* __restrict__ g, int G,
                                                 const unsigned* __restrict__ tsum,
                                                 unsigned* __restrict__ bstart, int NB, int n) {
    __shared__ unsigned s[256];
    const int t = threadIdx.x;
    const int base = blockIdx.x * TS + t * 8;
    unsigned v[8]; unsigned acc = 0;
#pragma unroll
    for (int j = 0; j < 8; ++j) { int gi = base + j; v[j] = (gi < G) ? g[gi] : 0u; acc += v[j]; }
    s[t] = acc; __syncthreads();
    for (int off = 1; off < 256; off <<= 1) {
        unsigned x = (t >= off) ? s[t - off] : 0u; __syncthreads();
        s[t] += x; __syncthreads();
    }
    unsigned excl = ((t == 0) ? 0u : s[t - 1]) + tsum[blockIdx.x];
#pragma unroll
    for (int j = 0; j < 8; ++j) {
        int gi = base + j;
        if (gi < G) {
            g[gi] = excl;
            if ((gi & (CB - 1)) == 0) bstart[gi / CB] = excl;
            excl += v[j];
        }
    }
    if (blockIdx.x == 0 && t == 0) bstart[NB] = (unsigned)n;
}

// K3: scatter records. pos = scanned[k][b] + LDS rank. No global atomics.
__global__ __launch_bounds__(256) void k3_scatter(const int* __restrict__ idx, int n, int chunk,
                                                  const unsigned* __restrict__ scanned,
                                                  unsigned* __restrict__ rec, int NB) {
    __shared__ unsigned cnt[NBMAX];
    __shared__ unsigned basel[NBMAX];
    const int b = blockIdx.x, t = threadIdx.x;
    for (int k = t; k < NB; k += 256) { basel[k] = scanned[(size_t)k * CB + b]; cnt[k] = 0u; }
    __syncthreads();
    const int lo = b * chunk, hi = min(n, lo + chunk);
    for (int i = lo + t; i < hi; i += 256) {
        unsigned pid = (unsigned)idx[i];
        unsigned k = pid >> 7;
        unsigned r = atomicAdd(&cnt[k], 1u);
        rec[basel[k] + r] = ((pid & 127u) << 22) | (unsigned)i;
    }
}

// ===========================================================================
// K4: per-bucket pool. In-LDS fine sort by pillar (lane-parallel), then
// windowed lane=point gather -> LDS, per-wave register max over sorted
// segments, one coalesced store per pillar. No global atomics.
// ===========================================================================
__global__ __launch_bounds__(256) void pool_sorted_kernel(
    const float* __restrict__ pts,
    const unsigned* __restrict__ rec,
    const unsigned* __restrict__ bstart,
    const float* __restrict__ W,
    const float* __restrict__ gamma, const float* __restrict__ beta,
    const float* __restrict__ mean, const float* __restrict__ var,
    float* __restrict__ out, int M)
{
    __shared__ float4  feat4[WIN * FSTR / 4];     // 12 KB, 48 B rows
    __shared__ unsigned seg_end[BP];              // inclusive ends
    __shared__ unsigned cnt[BP];
    __shared__ unsigned short ord[MAXB];
    __shared__ unsigned char  lpa[MAXB];
    float* feat = (float*)feat4;

    const int b = blockIdx.x;
    const int t = threadIdx.x;
    const int lane = t & 63;
    const int w = t >> 6;

    const unsigned base = bstart[b];
    const int T  = (int)(bstart[b + 1] - base);
    const int Tc = T < MAXB ? T : MAXB;
    const int npl = min(BP, M - b * BP);

    float wv[C_IN];
#pragma unroll
    for (int j = 0; j < C_IN; ++j) wv[j] = W[j * C_OUT + lane];
    const float scale = gamma[lane] * rsqrtf(var[lane] + BN_EPS);
    const float shift = fmaf(-mean[lane], scale, beta[lane]);

    // ---- fine sort by local pillar (all lane-parallel, LDS-only) ----
    if (t < BP) cnt[t] = 0u;
    __syncthreads();
    for (int r = t; r < Tc; r += 256) {
        unsigned l = rec[base + r] >> 22;
        lpa[r] = (unsigned char)l;
        atomicAdd(&cnt[l], 1u);
    }
    __syncthreads();
    if (t < BP) seg_end[t] = cnt[t];
    __syncthreads();
    for (int off = 1; off < BP; off <<= 1) {          // inclusive Hillis-Steele
        unsigned x = 0;
        if (t < BP && t >= off) x = seg_end[t - off];
        __syncthreads();
        if (t < BP) seg_end[t] += x;
        __syncthreads();
    }
    if (t < BP) cnt[t] = (t == 0) ? 0u : seg_end[t - 1];   // start cursors
    __syncthreads();
    for (int r = t; r < Tc; r += 256) {
        unsigned l = lpa[r];
        unsigned pos = atomicAdd(&cnt[l], 1u);
        ord[pos] = (unsigned short)r;
    }
    __syncthreads();

    // ---- windowed gather + per-wave register max ----
    float4 s0, s1; float2 s2; bool have = false;
    {
        const int Wn = Tc < WIN ? Tc : WIN;
        if (t < Wn) {
            unsigned rc = rec[base + ord[t]];
            const float2* f2 = (const float2*)(pts + (size_t)(rc & 0x3FFFFFu) * C_IN);
            float2 a0 = f2[0], a1 = f2[1], a2 = f2[2], a3 = f2[3], a4 = f2[4];
            s0 = make_float4(a0.x, a0.y, a1.x, a1.y);
            s1 = make_float4(a2.x, a2.y, a3.x, a3.y);
            s2 = a4; have = true;
        }
    }
    int p = w;
    float m = 0.f;
    const int nwin = (Tc + WIN - 1) / WIN;
    for (int k = 0; k < nwin; ++k) {
        const int W0 = k * WIN;
        const int Wn = (Tc - W0) < WIN ? (Tc - W0) : WIN;
        const int W1 = W0 + Wn;
        __syncthreads();                       // prev window fully consumed
        if (have) {
            float4* fp = (float4*)&feat[t * FSTR];
            fp[0] = s0; fp[1] = s1;
            *(float2*)&feat[t * FSTR + 8] = s2;
        }
        __syncthreads();
        // issue next window's loads now; latency hides under compute (T14)
        have = false;
        if (k + 1 < nwin) {
            const int NW0 = W0 + WIN;
            const int NWn = (Tc - NW0) < WIN ? (Tc - NW0) : WIN;
            if (t < NWn) {
                unsigned rc = rec[base + ord[NW0 + t]];
                const float2* f2 = (const float2*)(pts + (size_t)(rc & 0x3FFFFFu) * C_IN);
                float2 a0 = f2[0], a1 = f2[1], a2 = f2[2], a3 = f2[3], a4 = f2[4];
                s0 = make_float4(a0.x, a0.y, a1.x, a1.y);
                s1 = make_float4(a2.x, a2.y, a3.x, a3.y);
                s2 = a4; have = true;
            }
        }
        // consume: wave walks its pillars (p == w mod 4) over [W0, W1)
        while (p < npl) {
            int s = (p == 0) ? 0 : (int)seg_end[p - 1];
            if (s < W0) s = W0;
            const int e = (int)seg_end[p];
            const int eh = e < W1 ? e : W1;
            int j = s;
            for (; j + 1 < eh; j += 2) {
                const float4* F0 = (const float4*)&feat[(j - W0) * FSTR];
                const float4* F1 = (const float4*)&feat[(j + 1 - W0) * FSTR];
                float4 x0 = F0[0], x1 = F0[1];
                float2 x2 = *(const float2*)&feat[(j - W0) * FSTR + 8];
                float4 y0 = F1[0], y1 = F1[1];
                float2 y2 = *(const float2*)&feat[(j + 1 - W0) * FSTR + 8];
                float h0 = 0.f, h1 = 0.f;
                h0 = fmaf(x0.x, wv[0], h0); h0 = fmaf(x0.y, wv[1], h0);
                h0 = fmaf(x0.z, wv[2], h0); h0 = fmaf(x0.w, wv[3], h0);
                h0 = fmaf(x1.x, wv[4], h0); h0 = fmaf(x1.y, wv[5], h0);
                h0 = fmaf(x1.z, wv[6], h0); h0 = fmaf(x1.w, wv[7], h0);
                h0 = fmaf(x2.x, wv[8], h0); h0 = fmaf(x2.y, wv[9], h0);
                h1 = fmaf(y0.x, wv[0], h1); h1 = fmaf(y0.y, wv[1], h1);
                h1 = fmaf(y0.z, wv[2], h1); h1 = fmaf(y0.w, wv[3], h1);
                h1 = fmaf(y1.x, wv[4], h1); h1 = fmaf(y1.y, wv[5], h1);
                h1 = fmaf(y1.z, wv[6], h1); h1 = fmaf(y1.w, wv[7], h1);
                h1 = fmaf(y2.x, wv[8], h1); h1 = fmaf(y2.y, wv[9], h1);
                h0 = fmaxf(fmaf(h0, scale, shift), 0.f);
                h1 = fmaxf(fmaf(h1, scale, shift), 0.f);
                m = fmaxf(m, fmaxf(h0, h1));
            }
            if (j < eh) {
                const float4* F0 = (const float4*)&feat[(j - W0) * FSTR];
                float4 x0 = F0[0], x1 = F0[1];
                float2 x2 = *(const float2*)&feat[(j - W0) * FSTR + 8];
                float h0 = 0.f;
                h0 = fmaf(x0.x, wv[0], h0); h0 = fmaf(x0.y, wv[1], h0);
                h0 = fmaf(x0.z, wv[2], h0); h0 = fmaf(x0.w, wv[3], h0);
                h0 = fmaf(x1.x, wv[4], h0); h0 = fmaf(x1.y, wv[5], h0);
                h0 = fmaf(x1.z, wv[6], h0); h0 = fmaf(x1.w, wv[7], h0);
                h0 = fmaf(x2.x, wv[8], h0); h0 = fmaf(x2.y, wv[9], h0);
                m = fmaxf(m, fmaxf(fmaf(h0, scale, shift), 0.f));
            }
            if (e > W1) break;                 // pillar continues next window
            out[((size_t)(b * BP + p)) * C_OUT + lane] = m;
            m = 0.f; p += 4;
        }
    }
    // pillars untouched by windows (T==0 case)
    while (p < npl) {
        out[((size_t)(b * BP + p)) * C_OUT + lane] = m;
        m = 0.f; p += 4;
    }
    // overflow (T > MAXB): practically never; wave-owned plain RMW, race-free
    for (int r = MAXB; r < T; ++r) {
        unsigned rc = rec[base + r];
        const int l = (int)(rc >> 22);
        if ((l & 3) != w) continue;
        const float2* f2 = (const float2*)(pts + (size_t)(rc & 0x3FFFFFu) * C_IN);
        float2 a0 = f2[0], a1 = f2[1], a2 = f2[2], a3 = f2[3], a4 = f2[4];
        float h = 0.f;
        h = fmaf(a0.x, wv[0], h); h = fmaf(a0.y, wv[1], h);
        h = fmaf(a1.x, wv[2], h); h = fmaf(a1.y, wv[3], h);
        h = fmaf(a2.x, wv[4], h); h = fmaf(a2.y, wv[5], h);
        h = fmaf(a3.x, wv[6], h); h = fmaf(a3.y, wv[7], h);
        h = fmaf(a4.x, wv[8], h); h = fmaf(a4.y, wv[9], h);
        h = fmaxf(fmaf(h, scale, shift), 0.f);
        size_t o = ((size_t)(b * BP + l)) * C_OUT + lane;
        out[o] = fmaxf(out[o], h);
    }
}

// ===========================================================================
// FALLBACK 1: round-2 bucket path (known-good, ~384 us)
// ===========================================================================
#define CHUNK 256
#define FSTRIDE 11

__global__ __launch_bounds__(256) void zero_u32_kernel(unsigned* __restrict__ p, int n) {
    int i = blockIdx.x * 256 + threadIdx.x;
    int s = gridDim.x * 256;
    for (; i < n; i += s) p[i] = 0u;
}

__global__ __launch_bounds__(256) void hist_kernel(const int* __restrict__ idx, int n,
                                                   unsigned* __restrict__ hist, int nb) {
    __shared__ unsigned h[NBMAX];
    for (int i = threadIdx.x; i < nb; i += 256) h[i] = 0u;
    __syncthreads();
    int stride = gridDim.x * 256;
    for (int i = blockIdx.x * 256 + threadIdx.x; i < n; i += stride)
        atomicAdd(&h[((unsigned)idx[i]) >> 7], 1u);
    __syncthreads();
    for (int i = threadIdx.x; i < nb; i += 256) {
        unsigned v = h[i];
        if (v) atomicAdd(&hist[i], v);
    }
}

__global__ __launch_bounds__(256) void scan_kernel(const unsigned* __restrict__ hist,
                                                   unsigned* __restrict__ cursor, int nb) {
    __shared__ unsigned partial[256];
    __shared__ unsigned base[256];
    int per = (nb + 255) / 256;
    int lo = threadIdx.x * per;
    int hi = lo + per; if (hi > nb) hi = nb;
    unsigned s = 0;
    for (int i = lo; i < hi; ++i) s += hist[i];
    partial[threadIdx.x] = s;
    __syncthreads();
    if (threadIdx.x == 0) {
        unsigned acc = 0;
        for (int t = 0; t < 256; ++t) { base[t] = acc; acc += partial[t]; }
    }
    __syncthreads();
    unsigned acc = base[threadIdx.x];
    for (int i = lo; i < hi; ++i) { cursor[i] = acc; acc += hist[i]; }
}

__global__ __launch_bounds__(256) void scatter_ids_kernel(const int* __restrict__ idx, int n,
                                                          unsigned* __restrict__ cursor,
                                                          unsigned* __restrict__ rec) {
    int stride = gridDim.x * 256;
    for (int i = blockIdx.x * 256 + threadIdx.x; i < n; i += stride) {
        unsigned pid = (unsigned)idx[i];
        unsigned pos = atomicAdd(&cursor[pid >> 7], 1u);
        rec[pos] = ((pid & (BP - 1)) << 22) | (unsigned)i;
    }
}

__global__ __launch_bounds__(256) void pool_kernel(
    const float* __restrict__ pts, const unsigned* __restrict__ rec,
    const unsigned* __restrict__ cursor, const float* __restrict__ W,
    const float* __restrict__ gamma, const float* __restrict__ beta,
    const float* __restrict__ mean, const float* __restrict__ var,
    float* __restrict__ out, int M)
{
    __shared__ unsigned smax[BP * C_OUT];
    __shared__ float    feat[CHUNK * FSTRIDE];
    __shared__ unsigned slp[CHUNK];
    const int b = blockIdx.x, t = threadIdx.x;
    const int lane = t & 63, wid = t >> 6;
    for (int i = t; i < BP * C_OUT; i += 256) smax[i] = 0u;
    float w[C_IN];
#pragma unroll
    for (int j = 0; j < C_IN; ++j) w[j] = W[j * C_OUT + lane];
    const float scale = gamma[lane] * rsqrtf(var[lane] + BN_EPS);
    const float shift = fmaf(-mean[lane], scale, beta[lane]);
    const unsigned start = (b == 0) ? 0u : cursor[b - 1];
    const int total = (int)(cursor[b] - start);
    float fr[C_IN]; unsigned rcr = 0; bool hav = false;
    if (t < total) {
        rcr = rec[start + t];
        const float2* f2 = (const float2*)(pts + (size_t)(rcr & 0x3FFFFFu) * C_IN);
#pragma unroll
        for (int j = 0; j < 5; ++j) { float2 v = f2[j]; fr[2*j] = v.x; fr[2*j+1] = v.y; }
        hav = true;
    }
    for (int chunk = 0; chunk < total; chunk += CHUNK) {
        const int nrec = min(CHUNK, total - chunk);
        __syncthreads();
        if (hav) {
            slp[t] = rcr >> 22;
#pragma unroll
            for (int j = 0; j < C_IN; ++j) feat[t * FSTRIDE + j] = fr[j];
        }
        __syncthreads();
        const int nr = chunk + CHUNK + t;
        hav = false;
        if (nr < total) {
            rcr = rec[start + nr];
            const float2* f2 = (const float2*)(pts + (size_t)(rcr & 0x3FFFFFu) * C_IN);
#pragma unroll
            for (int j = 0; j < 5; ++j) { float2 v = f2[j]; fr[2*j] = v.x; fr[2*j+1] = v.y; }
            hav = true;
        }
        for (int i = wid; i < nrec; i += 4) {
            const unsigned lp = slp[i];
            const float* f = &feat[i * FSTRIDE];
            float h = 0.f;
#pragma unroll
            for (int j = 0; j < C_IN; ++j) h = fmaf(f[j], w[j], h);
            h = fmaxf(fmaf(h, scale, shift), 0.f);
            atomicMax(&smax[(lp << 6) + lane], __float_as_uint(h));
        }
    }
    __syncthreads();
    const float4* s4 = (const float4*)smax;
    float4* o4 = (float4*)out;
    const size_t base4 = (size_t)b * (BP * C_OUT / 4);
    const size_t tot4  = (size_t)M * (C_OUT / 4);
    for (int i = t; i < BP * C_OUT / 4; i += 256) {
        size_t g = base4 + (size_t)i;
        if (g < tot4) o4[g] = s4[i];
    }
}

// ===========================================================================
// FALLBACK 2: global atomic scatter (round-0)
// ===========================================================================
__global__ __launch_bounds__(256) void zero_out_kernel(float4* __restrict__ out4, int n4) {
    int i = blockIdx.x * blockDim.x + threadIdx.x;
    int stride = gridDim.x * blockDim.x;
    float4 z = make_float4(0.f, 0.f, 0.f, 0.f);
    for (int j = i; j < n4; j += stride) out4[j] = z;
}

__global__ __launch_bounds__(256) void pillar_scatter_kernel(
    const float* __restrict__ pts, const int* __restrict__ idx,
    const float* __restrict__ W, const float* __restrict__ gamma,
    const float* __restrict__ beta, const float* __restrict__ mean,
    const float* __restrict__ var, unsigned int* __restrict__ out, int npoints)
{
    const int lane = threadIdx.x & 63;
    float w[C_IN];
#pragma unroll
    for (int j = 0; j < C_IN; ++j) w[j] = W[j * C_OUT + lane];
    const float scale = gamma[lane] * rsqrtf(var[lane] + BN_EPS);
    const float shift = fmaf(-mean[lane], scale, beta[lane]);
    const int wave_id = (blockIdx.x * blockDim.x + threadIdx.x) >> 6;
    const int nwaves  = (gridDim.x * blockDim.x) >> 6;
    for (int p = wave_id; p < npoints; p += nwaves) {
        const float* f = pts + (size_t)p * C_IN;
        float h = 0.f;
#pragma unroll
        for (int j = 0; j < C_IN; ++j) h = fmaf(f[j], w[j], h);
        h = fmaxf(fmaf(h, scale, shift), 0.f);
        atomicMax(&out[(size_t)idx[p] * C_OUT + lane], __float_as_uint(h));
    }
}

// ===========================================================================

extern "C" void kernel_launch(void* const* d_in, const int* in_sizes, int n_in,
                              void* d_out, int out_size, void* d_ws, size_t ws_size,
                              hipStream_t stream) {
    const float* pts   = (const float*)d_in[0];
    const int*   idx   = (const int*)  d_in[1];
    const float* W     = (const float*)d_in[2];
    const float* gamma = (const float*)d_in[3];
    const float* beta  = (const float*)d_in[4];
    const float* mean  = (const float*)d_in[5];
    const float* var   = (const float*)d_in[6];

    const int npoints = in_sizes[0] / C_IN;     // 3,000,000
    const int M       = out_size / C_OUT;       // 600,000
    const int NB      = (M + BP - 1) / BP;      // 4688
    const int G       = NB * CB;                // 1.2M
    const int nt      = (G + TS - 1) / TS;      // 586
    const int chunk   = (npoints + CB - 1) / CB;

    // fast-path ws layout (u32): ghist[G] | tsum[nt] | bstart[NB+1] | pad | rec[n]
    const size_t rec_off = (((size_t)G + (size_t)nt + (size_t)NB + 1) + 63) & ~(size_t)63;
    const size_t need    = (rec_off + (size_t)npoints) * sizeof(unsigned);

    if (NB <= NBMAX && npoints < (1 << 22) && nt <= 65535 && ws_size >= need) {
        unsigned* ghist  = (unsigned*)d_ws;
        unsigned* tsum   = ghist + G;
        unsigned* bstart = tsum + nt;
        unsigned* rec    = (unsigned*)d_ws + rec_off;

        k1_hist          <<<CB, 256, 0, stream>>>(idx, npoints, chunk, ghist, NB);
        k2a_reduce       <<<nt, 256, 0, stream>>>(ghist, G, tsum);
        k2b_scan         <<<1,  256, 0, stream>>>(tsum, nt);
        k2c_apply        <<<nt, 256, 0, stream>>>(ghist, G, tsum, bstart, NB, npoints);
        k3_scatter       <<<CB, 256, 0, stream>>>(idx, npoints, chunk, ghist, rec, NB);
        pool_sorted_kernel<<<NB, 256, 0, stream>>>(pts, rec, bstart, W, gamma, beta,
                                                   mean, var, (float*)d_out, M);
        return;
    }

    // fallback 1: bucket path
    const size_t rec_off_f1 = ((size_t)(2 * NB) + 63) & ~(size_t)63;
    const size_t need_f1    = (rec_off_f1 + (size_t)npoints) * sizeof(unsigned);
    if (NB <= NBMAX && npoints < (1 << 22) && ws_size >= need_f1) {
        unsigned* cursor = (unsigned*)d_ws;
        unsigned* hist   = cursor + NB;
        unsigned* rec    = (unsigned*)d_ws + rec_off_f1;
        zero_u32_kernel<<<(2 * NB + 255) / 256, 256, 0, stream>>>(cursor, 2 * NB);
        hist_kernel<<<256, 256, 0, stream>>>(idx, npoints, hist, NB);
        scan_kernel<<<1, 256, 0, stream>>>(hist, cursor, NB);
        scatter_ids_kernel<<<2048, 256, 0, stream>>>(idx, npoints, cursor, rec);
        pool_kernel<<<NB, 256, 0, stream>>>(pts, rec, cursor, W, gamma, beta, mean, var,
                                            (float*)d_out, M);
        return;
    }

    // fallback 2: global atomics
    zero_out_kernel<<<2048, 256, 0, stream>>>((float4*)d_out, out_size / 4);
    pillar_scatter_kernel<<<2048, 256, 0, stream>>>(
        pts, idx, W, gamma, beta, mean, var, (unsigned int*)d_out, npoints);
}

// Round 6
// 219.384 us; speedup vs baseline: 3.4705x; 1.1119x over previous
//
#include <hip/hip_runtime.h>
#include <hip/hip_bf16.h>

#define C_IN 10
#define C_OUT 64
#define BN_EPS 1e-3f

#define BP    128         // pillars per bucket (idx>>7)
#define CB    256         // chunk blocks for hist/scatter
#define NBMAX 4704        // max buckets supported by fast path
#define TS    2048        // scan tile size

typedef __attribute__((ext_vector_type(8))) short bf16x8;
typedef __attribute__((ext_vector_type(4))) float f32x4;

// ===========================================================================
// ATOMIC-FREE SORT PROLOGUE (unchanged from R4 — proven)
// ws (u32): ghist[NB*CB] (scanned in place) | tsum[nt] | bstart[NB+1] | rec[n]
// ===========================================================================

__global__ __launch_bounds__(256) void k1_hist(const int* __restrict__ idx, int n, int chunk,
                                               unsigned* __restrict__ ghist, int NB) {
    __shared__ unsigned h[NBMAX];
    const int b = blockIdx.x, t = threadIdx.x;
    for (int i = t; i < NB; i += 256) h[i] = 0u;
    __syncthreads();
    const int lo = b * chunk;
    const int hi = min(n, lo + chunk);
    for (int i = lo + t; i < hi; i += 256)
        atomicAdd(&h[((unsigned)idx[i]) >> 7], 1u);
    __syncthreads();
    for (int k = t; k < NB; k += 256) ghist[(size_t)k * CB + b] = h[k];
}

__global__ __launch_bounds__(256) void k2a_reduce(const unsigned* __restrict__ g, int G,
                                                  unsigned* __restrict__ tsum) {
    __shared__ unsigned s[256];
    const int t = threadIdx.x;
    const int base = blockIdx.x * TS + t * 8;
    unsigned acc = 0;
#pragma unroll
    for (int j = 0; j < 8; ++j) { int gi = base + j; if (gi < G) acc += g[gi]; }
    s[t] = acc; __syncthreads();
    for (int off = 128; off > 0; off >>= 1) { if (t < off) s[t] += s[t + off]; __syncthreads(); }
    if (t == 0) tsum[blockIdx.x] = s[0];
}

__global__ __launch_bounds__(256) void k2b_scan(unsigned* __restrict__ tsum, int nt) {
    __shared__ unsigned partial[256], basev[256];
    const int t = threadIdx.x;
    const int per = (nt + 255) / 256;
    const int lo = t * per, hi = min(nt, lo + per);
    unsigned s = 0;
    for (int i = lo; i < hi; ++i) s += tsum[i];
    partial[t] = s; __syncthreads();
    if (t == 0) { unsigned a = 0; for (int k = 0; k < 256; ++k) { basev[k] = a; a += partial[k]; } }
    __syncthreads();
    unsigned a = basev[t];
    for (int i = lo; i < hi; ++i) { unsigned v = tsum[i]; tsum[i] = a; a += v; }
}

__global__ __launch_bounds__(256) void k2c_apply(unsigned* __restrict__ g, int G,
                                                 const unsigned* __restrict__ tsum,
                                                 unsigned* __restrict__ bstart, int NB, int n) {
    __shared__ unsigned s[256];
    const int t = threadIdx.x;
    const int base = blockIdx.x * TS + t * 8;
    unsigned v[8]; unsigned acc = 0;
#pragma unroll
    for (int j = 0; j < 8; ++j) { int gi = base + j; v[j] = (gi < G) ? g[gi] : 0u; acc += v[j]; }
    s[t] = acc; __syncthreads();
    for (int off = 1; off < 256; off <<= 1) {
        unsigned x = (t >= off) ? s[t - off] : 0u; __syncthreads();
        s[t] += x; __syncthreads();
    }
    unsigned excl = ((t == 0) ? 0u : s[t - 1]) + tsum[blockIdx.x];
#pragma unroll
    for (int j = 0; j < 8; ++j) {
        int gi = base + j;
        if (gi < G) {
            g[gi] = excl;
            if ((gi & (CB - 1)) == 0) bstart[gi / CB] = excl;
            excl += v[j];
        }
    }
    if (blockIdx.x == 0 && t == 0) bstart[NB] = (unsigned)n;
}

__global__ __launch_bounds__(256) void k3_scatter(const int* __restrict__ idx, int n, int chunk,
                                                  const unsigned* __restrict__ scanned,
                                                  unsigned* __restrict__ rec, int NB) {
    __shared__ unsigned cnt[NBMAX];
    __shared__ unsigned basel[NBMAX];
    const int b = blockIdx.x, t = threadIdx.x;
    for (int k = t; k < NB; k += 256) { basel[k] = scanned[(size_t)k * CB + b]; cnt[k] = 0u; }
    __syncthreads();
    const int lo = b * chunk, hi = min(n, lo + chunk);
    for (int i = lo + t; i < hi; i += 256) {
        unsigned pid = (unsigned)idx[i];
        unsigned k = pid >> 7;
        unsigned r = atomicAdd(&cnt[k], 1u);
        rec[basel[k] + r] = ((pid & 127u) << 22) | (unsigned)i;
    }
}

// ===========================================================================
// K4: per-bucket MFMA pool.
//   stage (lane=point): gather 40B row, cvt to bf16, write 32-bf16 A-row
//                       (k0..9 = feats, k10 = 1.0 for the BN-shift trick)
//   compute: 16x16x32 bf16 MFMA; B = W*diag(scale) with row k=10 = shift
//            -> output is BN-applied h directly
//   consume: relu fmax + LDS atomicMax into smax[pillar][ch]; row 128 = dummy
// ===========================================================================

static __device__ __forceinline__ unsigned pk2(float2 v) {
    __hip_bfloat162 h = __float22bfloat162_rn(v);
    return *reinterpret_cast<unsigned*>(&h);
}

__global__ __launch_bounds__(256) void pool_mfma_kernel(
    const float* __restrict__ pts,
    const unsigned* __restrict__ rec,
    const unsigned* __restrict__ bstart,
    const float* __restrict__ W,
    const float* __restrict__ gamma, const float* __restrict__ beta,
    const float* __restrict__ mean, const float* __restrict__ var,
    float* __restrict__ out, int M)
{
    __shared__ unsigned smax[129 * 64];       // 33 KB; rows 0..127 real, 128 dummy
    __shared__ unsigned astage[256 * 20];     // 20 KB; 80B rows: 16 u32 data + 4 pad
    __shared__ unsigned char slp[256];

    const int b = blockIdx.x;
    const int t = threadIdx.x;
    const int lane = t & 63;
    const int w = t >> 6;
    const int g  = lane >> 4;    // k-group (8 contiguous k's)
    const int c0 = lane & 15;

    // zero smax
    {
        uint4* s4 = (uint4*)smax;
        const uint4 z = make_uint4(0, 0, 0, 0);
        for (int i = t; i < 129 * 16; i += 256) s4[i] = z;
    }

    // B fragments: B'[k][ch] = W[k][ch]*scale[ch] (k<10), shift[ch] (k==10), 0 else
    bf16x8 bfrag[4];
#pragma unroll
    for (int tc = 0; tc < 4; ++tc) {
        const int ch = 16 * tc + c0;
        const float sc = gamma[ch] * rsqrtf(var[ch] + BN_EPS);
        const float sh = fmaf(-mean[ch], sc, beta[ch]);
        union { bf16x8 v; unsigned short u[8]; } B;
#pragma unroll
        for (int j = 0; j < 8; ++j) {
            const int k = g * 8 + j;
            float val = 0.f;
            if (k < 10) val = W[k * C_OUT + ch] * sc;
            else if (k == 10) val = sh;
            __hip_bfloat16 hb = __float2bfloat16(val);
            B.u[j] = *reinterpret_cast<unsigned short*>(&hb);
        }
        bfrag[tc] = B.v;
    }

    const unsigned base = bstart[b];
    const int T = (int)(bstart[b + 1] - base);
    const int nwin = (T + 255) >> 8;

    // prefetch window 0 (T14: regs now, LDS later)
    float2 pf0, pf1, pf2, pf3, pf4;
    unsigned prec = 0; bool have = false;
    if (t < T) {
        prec = rec[base + t];
        const float2* f2 = (const float2*)(pts + (size_t)(prec & 0x3FFFFFu) * C_IN);
        pf0 = f2[0]; pf1 = f2[1]; pf2 = f2[2]; pf3 = f2[3]; pf4 = f2[4];
        have = true;
    }

    for (int k = 0; k < nwin; ++k) {
        __syncthreads();                       // prior consume done (k=0: smax zero done)
        {
            uint4* ap = (uint4*)&astage[(unsigned)t * 20];
            const uint4 z = make_uint4(0, 0, 0, 0);
            if (have) {
                slp[t] = (unsigned char)(prec >> 22);
                ap[0] = make_uint4(pk2(pf0), pk2(pf1), pk2(pf2), pk2(pf3));
                ap[1] = make_uint4(pk2(pf4), 0x00003F80u /*k10=1.0*/, 0u, 0u);
            } else {
                slp[t] = 128;                  // dummy pillar row
                ap[0] = z; ap[1] = z;
            }
            ap[2] = z; ap[3] = z;
        }
        __syncthreads();
        // issue next window's gather now; hides under MFMA+consume
        have = false;
        {
            const int nr = (k + 1) * 256 + t;
            if (nr < T) {
                prec = rec[base + nr];
                const float2* f2 = (const float2*)(pts + (size_t)(prec & 0x3FFFFFu) * C_IN);
                pf0 = f2[0]; pf1 = f2[1]; pf2 = f2[2]; pf3 = f2[3]; pf4 = f2[4];
                have = true;
            }
        }
        // compute: wave w owns tiles [4w, 4w+4) of 16 points each
#pragma unroll
        for (int ti = 0; ti < 4; ++ti) {
            const int tbase = (4 * w + ti) * 16;
            union { uint4 q; bf16x8 v; } A;
            A.q = *(const uint4*)&astage[(unsigned)(tbase + c0) * 20 + (unsigned)(g * 4)];
            const f32x4 z4 = {0.f, 0.f, 0.f, 0.f};
            f32x4 a0 = __builtin_amdgcn_mfma_f32_16x16x32_bf16(A.v, bfrag[0], z4, 0, 0, 0);
            f32x4 a1 = __builtin_amdgcn_mfma_f32_16x16x32_bf16(A.v, bfrag[1], z4, 0, 0, 0);
            f32x4 a2 = __builtin_amdgcn_mfma_f32_16x16x32_bf16(A.v, bfrag[2], z4, 0, 0, 0);
            f32x4 a3 = __builtin_amdgcn_mfma_f32_16x16x32_bf16(A.v, bfrag[3], z4, 0, 0, 0);
#pragma unroll
            for (int r = 0; r < 4; ++r) {
                const int pt = tbase + g * 4 + r;          // C row = (lane>>4)*4 + r
                const unsigned lp = slp[pt];
                unsigned* srow = &smax[lp * 64 + c0];      // C col = lane&15 (+16*tc)
                atomicMax(&srow[0],  __float_as_uint(fmaxf(a0[r], 0.f)));
                atomicMax(&srow[16], __float_as_uint(fmaxf(a1[r], 0.f)));
                atomicMax(&srow[32], __float_as_uint(fmaxf(a2[r], 0.f)));
                atomicMax(&srow[48], __float_as_uint(fmaxf(a3[r], 0.f)));
            }
        }
    }
    __syncthreads();

    // writeout rows 0..127 (dummy row 128 skipped), coalesced b128
    const uint4* s4 = (const uint4*)smax;
    float4* o4 = (float4*)out;
    const size_t base4 = (size_t)b * (BP * C_OUT / 4);
    const size_t tot4  = (size_t)M * (C_OUT / 4);
    for (int i = t; i < BP * C_OUT / 4; i += 256) {
        size_t gi = base4 + (size_t)i;
        if (gi < tot4) {
            uint4 v = s4[i];
            o4[gi] = *reinterpret_cast<float4*>(&v);
        }
    }
}

// ===========================================================================
// FALLBACK 1: round-2 bucket path (known-good fp32, ~384 us)
// ===========================================================================
#define CHUNK 256
#define FSTRIDE 11

__global__ __launch_bounds__(256) void zero_u32_kernel(unsigned* __restrict__ p, int n) {
    int i = blockIdx.x * 256 + threadIdx.x;
    int s = gridDim.x * 256;
    for (; i < n; i += s) p[i] = 0u;
}

__global__ __launch_bounds__(256) void hist_kernel(const int* __restrict__ idx, int n,
                                                   unsigned* __restrict__ hist, int nb) {
    __shared__ unsigned h[NBMAX];
    for (int i = threadIdx.x; i < nb; i += 256) h[i] = 0u;
    __syncthreads();
    int stride = gridDim.x * 256;
    for (int i = blockIdx.x * 256 + threadIdx.x; i < n; i += stride)
        atomicAdd(&h[((unsigned)idx[i]) >> 7], 1u);
    __syncthreads();
    for (int i = threadIdx.x; i < nb; i += 256) {
        unsigned v = h[i];
        if (v) atomicAdd(&hist[i], v);
    }
}

__global__ __launch_bounds__(256) void scan_kernel(const unsigned* __restrict__ hist,
                                                   unsigned* __restrict__ cursor, int nb) {
    __shared__ unsigned partial[256];
    __shared__ unsigned base[256];
    int per = (nb + 255) / 256;
    int lo = threadIdx.x * per;
    int hi = lo + per; if (hi > nb) hi = nb;
    unsigned s = 0;
    for (int i = lo; i < hi; ++i) s += hist[i];
    partial[threadIdx.x] = s;
    __syncthreads();
    if (threadIdx.x == 0) {
        unsigned acc = 0;
        for (int t = 0; t < 256; ++t) { base[t] = acc; acc += partial[t]; }
    }
    __syncthreads();
    unsigned acc = base[threadIdx.x];
    for (int i = lo; i < hi; ++i) { cursor[i] = acc; acc += hist[i]; }
}

__global__ __launch_bounds__(256) void scatter_ids_kernel(const int* __restrict__ idx, int n,
                                                          unsigned* __restrict__ cursor,
                                                          unsigned* __restrict__ rec) {
    int stride = gridDim.x * 256;
    for (int i = blockIdx.x * 256 + threadIdx.x; i < n; i += stride) {
        unsigned pid = (unsigned)idx[i];
        unsigned pos = atomicAdd(&cursor[pid >> 7], 1u);
        rec[pos] = ((pid & (BP - 1)) << 22) | (unsigned)i;
    }
}

__global__ __launch_bounds__(256) void pool_kernel(
    const float* __restrict__ pts, const unsigned* __restrict__ rec,
    const unsigned* __restrict__ cursor, const float* __restrict__ W,
    const float* __restrict__ gamma, const float* __restrict__ beta,
    const float* __restrict__ mean, const float* __restrict__ var,
    float* __restrict__ out, int M)
{
    __shared__ unsigned smax[BP * C_OUT];
    __shared__ float    feat[CHUNK * FSTRIDE];
    __shared__ unsigned slp[CHUNK];
    const int b = blockIdx.x, t = threadIdx.x;
    const int lane = t & 63, wid = t >> 6;
    for (int i = t; i < BP * C_OUT; i += 256) smax[i] = 0u;
    float w[C_IN];
#pragma unroll
    for (int j = 0; j < C_IN; ++j) w[j] = W[j * C_OUT + lane];
    const float scale = gamma[lane] * rsqrtf(var[lane] + BN_EPS);
    const float shift = fmaf(-mean[lane], scale, beta[lane]);
    const unsigned start = (b == 0) ? 0u : cursor[b - 1];
    const int total = (int)(cursor[b] - start);
    float fr[C_IN]; unsigned rcr = 0; bool hav = false;
    if (t < total) {
        rcr = rec[start + t];
        const float2* f2 = (const float2*)(pts + (size_t)(rcr & 0x3FFFFFu) * C_IN);
#pragma unroll
        for (int j = 0; j < 5; ++j) { float2 v = f2[j]; fr[2*j] = v.x; fr[2*j+1] = v.y; }
        hav = true;
    }
    for (int chunk = 0; chunk < total; chunk += CHUNK) {
        const int nrec = min(CHUNK, total - chunk);
        __syncthreads();
        if (hav) {
            slp[t] = rcr >> 22;
#pragma unroll
            for (int j = 0; j < C_IN; ++j) feat[t * FSTRIDE + j] = fr[j];
        }
        __syncthreads();
        const int nr = chunk + CHUNK + t;
        hav = false;
        if (nr < total) {
            rcr = rec[start + nr];
            const float2* f2 = (const float2*)(pts + (size_t)(rcr & 0x3FFFFFu) * C_IN);
#pragma unroll
            for (int j = 0; j < 5; ++j) { float2 v = f2[j]; fr[2*j] = v.x; fr[2*j+1] = v.y; }
            hav = true;
        }
        for (int i = wid; i < nrec; i += 4) {
            const unsigned lp = slp[i];
            const float* f = &feat[i * FSTRIDE];
            float h = 0.f;
#pragma unroll
            for (int j = 0; j < C_IN; ++j) h = fmaf(f[j], w[j], h);
            h = fmaxf(fmaf(h, scale, shift), 0.f);
            atomicMax(&smax[(lp << 6) + lane], __float_as_uint(h));
        }
    }
    __syncthreads();
    const float4* s4 = (const float4*)smax;
    float4* o4 = (float4*)out;
    const size_t base4 = (size_t)b * (BP * C_OUT / 4);
    const size_t tot4  = (size_t)M * (C_OUT / 4);
    for (int i = t; i < BP * C_OUT / 4; i += 256) {
        size_t g = base4 + (size_t)i;
        if (g < tot4) o4[g] = s4[i];
    }
}

// ===========================================================================
// FALLBACK 2: global atomic scatter (round-0)
// ===========================================================================
__global__ __launch_bounds__(256) void zero_out_kernel(float4* __restrict__ out4, int n4) {
    int i = blockIdx.x * blockDim.x + threadIdx.x;
    int stride = gridDim.x * blockDim.x;
    float4 z = make_float4(0.f, 0.f, 0.f, 0.f);
    for (int j = i; j < n4; j += stride) out4[j] = z;
}

__global__ __launch_bounds__(256) void pillar_scatter_kernel(
    const float* __restrict__ pts, const int* __restrict__ idx,
    const float* __restrict__ W, const float* __restrict__ gamma,
    const float* __restrict__ beta, const float* __restrict__ mean,
    const float* __restrict__ var, unsigned int* __restrict__ out, int npoints)
{
    const int lane = threadIdx.x & 63;
    float w[C_IN];
#pragma unroll
    for (int j = 0; j < C_IN; ++j) w[j] = W[j * C_OUT + lane];
    const float scale = gamma[lane] * rsqrtf(var[lane] + BN_EPS);
    const float shift = fmaf(-mean[lane], scale, beta[lane]);
    const int wave_id = (blockIdx.x * blockDim.x + threadIdx.x) >> 6;
    const int nwaves  = (gridDim.x * blockDim.x) >> 6;
    for (int p = wave_id; p < npoints; p += nwaves) {
        const float* f = pts + (size_t)p * C_IN;
        float h = 0.f;
#pragma unroll
        for (int j = 0; j < C_IN; ++j) h = fmaf(f[j], w[j], h);
        h = fmaxf(fmaf(h, scale, shift), 0.f);
        atomicMax(&out[(size_t)idx[p] * C_OUT + lane], __float_as_uint(h));
    }
}

// ===========================================================================

extern "C" void kernel_launch(void* const* d_in, const int* in_sizes, int n_in,
                              void* d_out, int out_size, void* d_ws, size_t ws_size,
                              hipStream_t stream) {
    const float* pts   = (const float*)d_in[0];
    const int*   idx   = (const int*)  d_in[1];
    const float* W     = (const float*)d_in[2];
    const float* gamma = (const float*)d_in[3];
    const float* beta  = (const float*)d_in[4];
    const float* mean  = (const float*)d_in[5];
    const float* var   = (const float*)d_in[6];

    const int npoints = in_sizes[0] / C_IN;     // 3,000,000
    const int M       = out_size / C_OUT;       // 600,000
    const int NB      = (M + BP - 1) / BP;      // 4688
    const int G       = NB * CB;                // 1.2M
    const int nt      = (G + TS - 1) / TS;      // 586
    const int chunk   = (npoints + CB - 1) / CB;

    // fast-path ws layout (u32): ghist[G] | tsum[nt] | bstart[NB+1] | pad | rec[n]
    const size_t rec_off = (((size_t)G + (size_t)nt + (size_t)NB + 1) + 63) & ~(size_t)63;
    const size_t need    = (rec_off + (size_t)npoints) * sizeof(unsigned);

    if (NB <= NBMAX && npoints < (1 << 22) && nt <= 65535 && ws_size >= need) {
        unsigned* ghist  = (unsigned*)d_ws;
        unsigned* tsum   = ghist + G;
        unsigned* bstart = tsum + nt;
        unsigned* rec    = (unsigned*)d_ws + rec_off;

        k1_hist          <<<CB, 256, 0, stream>>>(idx, npoints, chunk, ghist, NB);
        k2a_reduce       <<<nt, 256, 0, stream>>>(ghist, G, tsum);
        k2b_scan         <<<1,  256, 0, stream>>>(tsum, nt);
        k2c_apply        <<<nt, 256, 0, stream>>>(ghist, G, tsum, bstart, NB, npoints);
        k3_scatter       <<<CB, 256, 0, stream>>>(idx, npoints, chunk, ghist, rec, NB);
        pool_mfma_kernel <<<NB, 256, 0, stream>>>(pts, rec, bstart, W, gamma, beta,
                                                  mean, var, (float*)d_out, M);
        return;
    }

    // fallback 1: bucket path (fp32)
    const size_t rec_off_f1 = ((size_t)(2 * NB) + 63) & ~(size_t)63;
    const size_t need_f1    = (rec_off_f1 + (size_t)npoints) * sizeof(unsigned);
    if (NB <= NBMAX && npoints < (1 << 22) && ws_size >= need_f1) {
        unsigned* cursor = (unsigned*)d_ws;
        unsigned* hist   = cursor + NB;
        unsigned* rec    = (unsigned*)d_ws + rec_off_f1;
        zero_u32_kernel<<<(2 * NB + 255) / 256, 256, 0, stream>>>(cursor, 2 * NB);
        hist_kernel<<<256, 256, 0, stream>>>(idx, npoints, hist, NB);
        scan_kernel<<<1, 256, 0, stream>>>(hist, cursor, NB);
        scatter_ids_kernel<<<2048, 256, 0, stream>>>(idx, npoints, cursor, rec);
        pool_kernel<<<NB, 256, 0, stream>>>(pts, rec, cursor, W, gamma, beta, mean, var,
                                            (float*)d_out, M);
        return;
    }

    // fallback 2: global atomics
    zero_out_kernel<<<2048, 256, 0, stream>>>((float4*)d_out, out_size / 4);
    pillar_scatter_kernel<<<2048, 256, 0, stream>>>(
        pts, idx, W, gamma, beta, mean, var, (unsigned int*)d_out, npoints);
}

// Round 7
// 210.830 us; speedup vs baseline: 3.6113x; 1.0406x over previous
//
#include <hip/hip_runtime.h>
#include <hip/hip_bf16.h>

#define C_IN 10
#define C_OUT 64
#define BN_EPS 1e-3f

#define BP    128         // pillars per bucket (idx>>7)
#define CB    256         // chunk blocks for hist/scatter
#define NBMAX 4704        // max buckets supported by fast path
#define TS    2048        // scan tile size

typedef __attribute__((ext_vector_type(8))) short bf16x8;
typedef __attribute__((ext_vector_type(4))) float f32x4;

// ===========================================================================
// ATOMIC-FREE SORT PROLOGUE (unchanged — proven)
// ws (u32): ghist[NB*CB] (scanned in place) | tsum[nt] | bstart[NB+1] | rec[n]
// ===========================================================================

__global__ __launch_bounds__(256) void k1_hist(const int* __restrict__ idx, int n, int chunk,
                                               unsigned* __restrict__ ghist, int NB) {
    __shared__ unsigned h[NBMAX];
    const int b = blockIdx.x, t = threadIdx.x;
    for (int i = t; i < NB; i += 256) h[i] = 0u;
    __syncthreads();
    const int lo = b * chunk;
    const int hi = min(n, lo + chunk);
    for (int i = lo + t; i < hi; i += 256)
        atomicAdd(&h[((unsigned)idx[i]) >> 7], 1u);
    __syncthreads();
    for (int k = t; k < NB; k += 256) ghist[(size_t)k * CB + b] = h[k];
}

__global__ __launch_bounds__(256) void k2a_reduce(const unsigned* __restrict__ g, int G,
                                                  unsigned* __restrict__ tsum) {
    __shared__ unsigned s[256];
    const int t = threadIdx.x;
    const int base = blockIdx.x * TS + t * 8;
    unsigned acc = 0;
#pragma unroll
    for (int j = 0; j < 8; ++j) { int gi = base + j; if (gi < G) acc += g[gi]; }
    s[t] = acc; __syncthreads();
    for (int off = 128; off > 0; off >>= 1) { if (t < off) s[t] += s[t + off]; __syncthreads(); }
    if (t == 0) tsum[blockIdx.x] = s[0];
}

__global__ __launch_bounds__(256) void k2b_scan(unsigned* __restrict__ tsum, int nt) {
    __shared__ unsigned partial[256], basev[256];
    const int t = threadIdx.x;
    const int per = (nt + 255) / 256;
    const int lo = t * per, hi = min(nt, lo + per);
    unsigned s = 0;
    for (int i = lo; i < hi; ++i) s += tsum[i];
    partial[t] = s; __syncthreads();
    if (t == 0) { unsigned a = 0; for (int k = 0; k < 256; ++k) { basev[k] = a; a += partial[k]; } }
    __syncthreads();
    unsigned a = basev[t];
    for (int i = lo; i < hi; ++i) { unsigned v = tsum[i]; tsum[i] = a; a += v; }
}

__global__ __launch_bounds__(256) void k2c_apply(unsigned* __restrict__ g, int G,
                                                 const unsigned* __restrict__ tsum,
                                                 unsigned* __restrict__ bstart, int NB, int n) {
    __shared__ unsigned s[256];
    const int t = threadIdx.x;
    const int base = blockIdx.x * TS + t * 8;
    unsigned v[8]; unsigned acc = 0;
#pragma unroll
    for (int j = 0; j < 8; ++j) { int gi = base + j; v[j] = (gi < G) ? g[gi] : 0u; acc += v[j]; }
    s[t] = acc; __syncthreads();
    for (int off = 1; off < 256; off <<= 1) {
        unsigned x = (t >= off) ? s[t - off] : 0u; __syncthreads();
        s[t] += x; __syncthreads();
    }
    unsigned excl = ((t == 0) ? 0u : s[t - 1]) + tsum[blockIdx.x];
#pragma unroll
    for (int j = 0; j < 8; ++j) {
        int gi = base + j;
        if (gi < G) {
            g[gi] = excl;
            if ((gi & (CB - 1)) == 0) bstart[gi / CB] = excl;
            excl += v[j];
        }
    }
    if (blockIdx.x == 0 && t == 0) bstart[NB] = (unsigned)n;
}

__global__ __launch_bounds__(256) void k3_scatter(const int* __restrict__ idx, int n, int chunk,
                                                  const unsigned* __restrict__ scanned,
                                                  unsigned* __restrict__ rec, int NB) {
    __shared__ unsigned cnt[NBMAX];
    __shared__ unsigned basel[NBMAX];
    const int b = blockIdx.x, t = threadIdx.x;
    for (int k = t; k < NB; k += 256) { basel[k] = scanned[(size_t)k * CB + b]; cnt[k] = 0u; }
    __syncthreads();
    const int lo = b * chunk, hi = min(n, lo + chunk);
    for (int i = lo + t; i < hi; i += 256) {
        unsigned pid = (unsigned)idx[i];
        unsigned k = pid >> 7;
        unsigned r = atomicAdd(&cnt[k], 1u);
        rec[basel[k] + r] = ((pid & 127u) << 22) | (unsigned)i;
    }
}

// ===========================================================================
// K4 v2: barrier-free MFMA pool.
//   - wave-autonomous: wave w's 4 MFMA tiles consume exactly wave w's own
//     64 gathered points -> A-frag redistribution via __shfl (no LDS stage,
//     no __syncthreads in the loop)
//   - smax rows rotated by 4*lp words: bank = (ch + 4*lp) % 32 -> random-lp
//     g-groups spread across banks (kills R5's 8.1M conflicts)
//   - out-of-range lanes clamp to point T-1 (max is idempotent)
//   - LDS = 32 KB -> 4 blocks/CU
// ===========================================================================

static __device__ __forceinline__ unsigned pk2(float2 v) {
    __hip_bfloat162 h = __float22bfloat162_rn(v);
    return *reinterpret_cast<unsigned*>(&h);
}

__global__ __launch_bounds__(256) void pool_mfma2_kernel(
    const float* __restrict__ pts,
    const unsigned* __restrict__ rec,
    const unsigned* __restrict__ bstart,
    const float* __restrict__ W,
    const float* __restrict__ gamma, const float* __restrict__ beta,
    const float* __restrict__ mean, const float* __restrict__ var,
    float* __restrict__ out, int M)
{
    __shared__ unsigned smax[BP * C_OUT];         // 32 KB, rows rotated by 4*lp

    const int b = blockIdx.x, t = threadIdx.x;
    const int lane = t & 63, w = t >> 6;
    const int g = lane >> 4, c0 = lane & 15;

    uint4* s4 = (uint4*)smax;
    const uint4 zq = make_uint4(0u, 0u, 0u, 0u);
    for (int i = t; i < BP * C_OUT / 4; i += 256) s4[i] = zq;

    // B' = W*diag(scale), row k=10 = shift (A k10 = 1.0), rows 11..31 = 0
    bf16x8 bfrag[4];
#pragma unroll
    for (int tc = 0; tc < 4; ++tc) {
        const int ch = 16 * tc + c0;
        const float sc = gamma[ch] * rsqrtf(var[ch] + BN_EPS);
        const float sh = fmaf(-mean[ch], sc, beta[ch]);
        union { bf16x8 v; unsigned short u[8]; } B;
#pragma unroll
        for (int j = 0; j < 8; ++j) {
            const int k = g * 8 + j;
            float val = 0.f;
            if (k < 10) val = W[k * C_OUT + ch] * sc;
            else if (k == 10) val = sh;
            __hip_bfloat16 hb = __float2bfloat16(val);
            B.u[j] = *reinterpret_cast<unsigned short*>(&hb);
        }
        bfrag[tc] = B.v;
    }

    const unsigned base = bstart[b];
    const int T = (int)(bstart[b + 1] - base);

    __syncthreads();                               // smax zero visible

    // prefetch this wave's window 0
    float2 pf0, pf1, pf2, pf3, pf4;
    unsigned rc = 0u;
    if (w * 64 < T) {
        const int i = min(w * 64 + lane, T - 1);   // idempotent clamp
        rc = rec[base + i];
        const float2* f2 = (const float2*)(pts + (size_t)(rc & 0x3FFFFFu) * C_IN);
        pf0 = f2[0]; pf1 = f2[1]; pf2 = f2[2]; pf3 = f2[3]; pf4 = f2[4];
    }

    for (int k = 0; w * 64 + k * 256 < T; ++k) {
        // pack current window to bf16 (k0..9 feats; k10=1.0 const; k11..31=0)
        const unsigned p0 = pk2(pf0), p1 = pk2(pf1), p2 = pk2(pf2),
                       p3 = pk2(pf3), p4 = pk2(pf4);
        const int lpv = (int)(rc >> 22);

        // issue next window's gather now; hides under shfl/MFMA/atomics (T14)
        const int nb_ = w * 64 + (k + 1) * 256;
        if (nb_ < T) {
            const int i = min(nb_ + lane, T - 1);
            rc = rec[base + i];
            const float2* f2 = (const float2*)(pts + (size_t)(rc & 0x3FFFFFu) * C_IN);
            pf0 = f2[0]; pf1 = f2[1]; pf2 = f2[2]; pf3 = f2[3]; pf4 = f2[4];
        }

#pragma unroll
        for (int ti = 0; ti < 4; ++ti) {
            // A frag: row c0 of tile ti = this wave's lane ti*16+c0
            const int srcA = ti * 16 + c0;
            const unsigned s0 = (unsigned)__shfl((int)p0, srcA);
            const unsigned s1 = (unsigned)__shfl((int)p1, srcA);
            const unsigned s2 = (unsigned)__shfl((int)p2, srcA);
            const unsigned s3 = (unsigned)__shfl((int)p3, srcA);
            const unsigned s4v = (unsigned)__shfl((int)p4, srcA);
            union { uint4 q; bf16x8 v; } A;
            if (g == 0)      A.q = make_uint4(s0, s1, s2, s3);
            else if (g == 1) A.q = make_uint4(s4v, 0x00003F80u, 0u, 0u);
            else             A.q = make_uint4(0u, 0u, 0u, 0u);

            const f32x4 z4 = {0.f, 0.f, 0.f, 0.f};
            f32x4 a0 = __builtin_amdgcn_mfma_f32_16x16x32_bf16(A.v, bfrag[0], z4, 0, 0, 0);
            f32x4 a1 = __builtin_amdgcn_mfma_f32_16x16x32_bf16(A.v, bfrag[1], z4, 0, 0, 0);
            f32x4 a2 = __builtin_amdgcn_mfma_f32_16x16x32_bf16(A.v, bfrag[2], z4, 0, 0, 0);
            f32x4 a3 = __builtin_amdgcn_mfma_f32_16x16x32_bf16(A.v, bfrag[3], z4, 0, 0, 0);

            // C rows owned by this lane: points ti*16 + g*4 + r
            const int sb = ti * 16 + g * 4;
            const int l0 = __shfl(lpv, sb + 0);
            const int l1 = __shfl(lpv, sb + 1);
            const int l2 = __shfl(lpv, sb + 2);
            const int l3 = __shfl(lpv, sb + 3);

#define CONSUME_R(LP, R) { \
            unsigned* rowp = &smax[((unsigned)(LP)) << 6]; \
            const unsigned rb = (unsigned)(c0 + ((LP) << 2)); \
            atomicMax(&rowp[(rb +  0u) & 63u], __float_as_uint(fmaxf(a0[R], 0.f))); \
            atomicMax(&rowp[(rb + 16u) & 63u], __float_as_uint(fmaxf(a1[R], 0.f))); \
            atomicMax(&rowp[(rb + 32u) & 63u], __float_as_uint(fmaxf(a2[R], 0.f))); \
            atomicMax(&rowp[(rb + 48u) & 63u], __float_as_uint(fmaxf(a3[R], 0.f))); }
            CONSUME_R(l0, 0); CONSUME_R(l1, 1); CONSUME_R(l2, 2); CONSUME_R(l3, 3);
#undef CONSUME_R
        }
    }
    __syncthreads();

    // writeout with un-rotation: phys quad q of row lp -> out quad (q - lp) & 15
    const int row = t >> 1;
    const int half = t & 1;
    const int gp = b * BP + row;
    if (gp < M) {
        float4* o4 = (float4*)out;
        const size_t ob = (size_t)gp * (C_OUT / 4);
#pragma unroll
        for (int j = 0; j < 8; ++j) {
            const int q = half * 8 + j;
            uint4 v = s4[row * 16 + q];
            const int oq = (q - row) & 15;
            o4[ob + oq] = *reinterpret_cast<float4*>(&v);
        }
    }
}

// ===========================================================================
// FALLBACK 1: round-2 bucket path (known-good fp32)
// ===========================================================================
#define CHUNK 256
#define FSTRIDE 11

__global__ __launch_bounds__(256) void zero_u32_kernel(unsigned* __restrict__ p, int n) {
    int i = blockIdx.x * 256 + threadIdx.x;
    int s = gridDim.x * 256;
    for (; i < n; i += s) p[i] = 0u;
}

__global__ __launch_bounds__(256) void hist_kernel(const int* __restrict__ idx, int n,
                                                   unsigned* __restrict__ hist, int nb) {
    __shared__ unsigned h[NBMAX];
    for (int i = threadIdx.x; i < nb; i += 256) h[i] = 0u;
    __syncthreads();
    int stride = gridDim.x * 256;
    for (int i = blockIdx.x * 256 + threadIdx.x; i < n; i += stride)
        atomicAdd(&h[((unsigned)idx[i]) >> 7], 1u);
    __syncthreads();
    for (int i = threadIdx.x; i < nb; i += 256) {
        unsigned v = h[i];
        if (v) atomicAdd(&hist[i], v);
    }
}

__global__ __launch_bounds__(256) void scan_kernel(const unsigned* __restrict__ hist,
                                                   unsigned* __restrict__ cursor, int nb) {
    __shared__ unsigned partial[256];
    __shared__ unsigned base[256];
    int per = (nb + 255) / 256;
    int lo = threadIdx.x * per;
    int hi = lo + per; if (hi > nb) hi = nb;
    unsigned s = 0;
    for (int i = lo; i < hi; ++i) s += hist[i];
    partial[threadIdx.x] = s;
    __syncthreads();
    if (threadIdx.x == 0) {
        unsigned acc = 0;
        for (int t = 0; t < 256; ++t) { base[t] = acc; acc += partial[t]; }
    }
    __syncthreads();
    unsigned acc = base[threadIdx.x];
    for (int i = lo; i < hi; ++i) { cursor[i] = acc; acc += hist[i]; }
}

__global__ __launch_bounds__(256) void scatter_ids_kernel(const int* __restrict__ idx, int n,
                                                          unsigned* __restrict__ cursor,
                                                          unsigned* __restrict__ rec) {
    int stride = gridDim.x * 256;
    for (int i = blockIdx.x * 256 + threadIdx.x; i < n; i += stride) {
        unsigned pid = (unsigned)idx[i];
        unsigned pos = atomicAdd(&cursor[pid >> 7], 1u);
        rec[pos] = ((pid & (BP - 1)) << 22) | (unsigned)i;
    }
}

__global__ __launch_bounds__(256) void pool_kernel(
    const float* __restrict__ pts, const unsigned* __restrict__ rec,
    const unsigned* __restrict__ cursor, const float* __restrict__ W,
    const float* __restrict__ gamma, const float* __restrict__ beta,
    const float* __restrict__ mean, const float* __restrict__ var,
    float* __restrict__ out, int M)
{
    __shared__ unsigned smax[BP * C_OUT];
    __shared__ float    feat[CHUNK * FSTRIDE];
    __shared__ unsigned slp[CHUNK];
    const int b = blockIdx.x, t = threadIdx.x;
    const int lane = t & 63, wid = t >> 6;
    for (int i = t; i < BP * C_OUT; i += 256) smax[i] = 0u;
    float w[C_IN];
#pragma unroll
    for (int j = 0; j < C_IN; ++j) w[j] = W[j * C_OUT + lane];
    const float scale = gamma[lane] * rsqrtf(var[lane] + BN_EPS);
    const float shift = fmaf(-mean[lane], scale, beta[lane]);
    const unsigned start = (b == 0) ? 0u : cursor[b - 1];
    const int total = (int)(cursor[b] - start);
    float fr[C_IN]; unsigned rcr = 0; bool hav = false;
    if (t < total) {
        rcr = rec[start + t];
        const float2* f2 = (const float2*)(pts + (size_t)(rcr & 0x3FFFFFu) * C_IN);
#pragma unroll
        for (int j = 0; j < 5; ++j) { float2 v = f2[j]; fr[2*j] = v.x; fr[2*j+1] = v.y; }
        hav = true;
    }
    for (int chunk = 0; chunk < total; chunk += CHUNK) {
        const int nrec = min(CHUNK, total - chunk);
        __syncthreads();
        if (hav) {
            slp[t] = rcr >> 22;
#pragma unroll
            for (int j = 0; j < C_IN; ++j) feat[t * FSTRIDE + j] = fr[j];
        }
        __syncthreads();
        const int nr = chunk + CHUNK + t;
        hav = false;
        if (nr < total) {
            rcr = rec[start + nr];
            const float2* f2 = (const float2*)(pts + (size_t)(rcr & 0x3FFFFFu) * C_IN);
#pragma unroll
            for (int j = 0; j < 5; ++j) { float2 v = f2[j]; fr[2*j] = v.x; fr[2*j+1] = v.y; }
            hav = true;
        }
        for (int i = wid; i < nrec; i += 4) {
            const unsigned lp = slp[i];
            const float* f = &feat[i * FSTRIDE];
            float h = 0.f;
#pragma unroll
            for (int j = 0; j < C_IN; ++j) h = fmaf(f[j], w[j], h);
            h = fmaxf(fmaf(h, scale, shift), 0.f);
            atomicMax(&smax[(lp << 6) + lane], __float_as_uint(h));
        }
    }
    __syncthreads();
    const float4* sf4 = (const float4*)smax;
    float4* o4 = (float4*)out;
    const size_t base4 = (size_t)b * (BP * C_OUT / 4);
    const size_t tot4  = (size_t)M * (C_OUT / 4);
    for (int i = t; i < BP * C_OUT / 4; i += 256) {
        size_t gq = base4 + (size_t)i;
        if (gq < tot4) o4[gq] = sf4[i];
    }
}

// ===========================================================================
// FALLBACK 2: global atomic scatter (round-0)
// ===========================================================================
__global__ __launch_bounds__(256) void zero_out_kernel(float4* __restrict__ out4, int n4) {
    int i = blockIdx.x * blockDim.x + threadIdx.x;
    int stride = gridDim.x * blockDim.x;
    float4 z = make_float4(0.f, 0.f, 0.f, 0.f);
    for (int j = i; j < n4; j += stride) out4[j] = z;
}

__global__ __launch_bounds__(256) void pillar_scatter_kernel(
    const float* __restrict__ pts, const int* __restrict__ idx,
    const float* __restrict__ W, const float* __restrict__ gamma,
    const float* __restrict__ beta, const float* __restrict__ mean,
    const float* __restrict__ var, unsigned int* __restrict__ out, int npoints)
{
    const int lane = threadIdx.x & 63;
    float w[C_IN];
#pragma unroll
    for (int j = 0; j < C_IN; ++j) w[j] = W[j * C_OUT + lane];
    const float scale = gamma[lane] * rsqrtf(var[lane] + BN_EPS);
    const float shift = fmaf(-mean[lane], scale, beta[lane]);
    const int wave_id = (blockIdx.x * blockDim.x + threadIdx.x) >> 6;
    const int nwaves  = (gridDim.x * blockDim.x) >> 6;
    for (int p = wave_id; p < npoints; p += nwaves) {
        const float* f = pts + (size_t)p * C_IN;
        float h = 0.f;
#pragma unroll
        for (int j = 0; j < C_IN; ++j) h = fmaf(f[j], w[j], h);
        h = fmaxf(fmaf(h, scale, shift), 0.f);
        atomicMax(&out[(size_t)idx[p] * C_OUT + lane], __float_as_uint(h));
    }
}

// ===========================================================================

extern "C" void kernel_launch(void* const* d_in, const int* in_sizes, int n_in,
                              void* d_out, int out_size, void* d_ws, size_t ws_size,
                              hipStream_t stream) {
    const float* pts   = (const float*)d_in[0];
    const int*   idx   = (const int*)  d_in[1];
    const float* W     = (const float*)d_in[2];
    const float* gamma = (const float*)d_in[3];
    const float* beta  = (const float*)d_in[4];
    const float* mean  = (const float*)d_in[5];
    const float* var   = (const float*)d_in[6];

    const int npoints = in_sizes[0] / C_IN;     // 3,000,000
    const int M       = out_size / C_OUT;       // 600,000
    const int NB      = (M + BP - 1) / BP;      // 4688
    const int G       = NB * CB;                // 1.2M
    const int nt      = (G + TS - 1) / TS;      // 586
    const int chunk   = (npoints + CB - 1) / CB;

    // fast-path ws layout (u32): ghist[G] | tsum[nt] | bstart[NB+1] | pad | rec[n]
    const size_t rec_off = (((size_t)G + (size_t)nt + (size_t)NB + 1) + 63) & ~(size_t)63;
    const size_t need    = (rec_off + (size_t)npoints) * sizeof(unsigned);

    if (NB <= NBMAX && npoints < (1 << 22) && nt <= 65535 && ws_size >= need) {
        unsigned* ghist  = (unsigned*)d_ws;
        unsigned* tsum   = ghist + G;
        unsigned* bstart = tsum + nt;
        unsigned* rec    = (unsigned*)d_ws + rec_off;

        k1_hist           <<<CB, 256, 0, stream>>>(idx, npoints, chunk, ghist, NB);
        k2a_reduce        <<<nt, 256, 0, stream>>>(ghist, G, tsum);
        k2b_scan          <<<1,  256, 0, stream>>>(tsum, nt);
        k2c_apply         <<<nt, 256, 0, stream>>>(ghist, G, tsum, bstart, NB, npoints);
        k3_scatter        <<<CB, 256, 0, stream>>>(idx, npoints, chunk, ghist, rec, NB);
        pool_mfma2_kernel <<<NB, 256, 0, stream>>>(pts, rec, bstart, W, gamma, beta,
                                                   mean, var, (float*)d_out, M);
        return;
    }

    // fallback 1: bucket path (fp32)
    const size_t rec_off_f1 = ((size_t)(2 * NB) + 63) & ~(size_t)63;
    const size_t need_f1    = (rec_off_f1 + (size_t)npoints) * sizeof(unsigned);
    if (NB <= NBMAX && npoints < (1 << 22) && ws_size >= need_f1) {
        unsigned* cursor = (unsigned*)d_ws;
        unsigned* hist   = cursor + NB;
        unsigned* rec    = (unsigned*)d_ws + rec_off_f1;
        zero_u32_kernel<<<(2 * NB + 255) / 256, 256, 0, stream>>>(cursor, 2 * NB);
        hist_kernel<<<256, 256, 0, stream>>>(idx, npoints, hist, NB);
        scan_kernel<<<1, 256, 0, stream>>>(hist, cursor, NB);
        scatter_ids_kernel<<<2048, 256, 0, stream>>>(idx, npoints, cursor, rec);
        pool_kernel<<<NB, 256, 0, stream>>>(pts, rec, cursor, W, gamma, beta, mean, var,
                                            (float*)d_out, M);
        return;
    }

    // fallback 2: global atomics
    zero_out_kernel<<<2048, 256, 0, stream>>>((float4*)d_out, out_size / 4);
    pillar_scatter_kernel<<<2048, 256, 0, stream>>>(
        pts, idx, W, gamma, beta, mean, var, (unsigned int*)d_out, npoints);
}